// Round 5
// baseline (564.798 us; speedup 1.0000x reference)
//
#include <hip/hip_runtime.h>
#include <hip/hip_bf16.h>
#include <cstddef>
#include <cstdint>

#define B_   8
#define CIN  96
#define H_   256
#define W_   256
#define CO1  48          // conv1 output channels
#define NCH  192         // final output channels (CO1*4)
#define HO   128
#define WO   128

// conv1 LDS row slot: 258 px-major cells of 12 chunks (8 bf16 = 16B cell),
// swizzled: cell(px,c) at px*192 + ((c ^ (px&3))<<4).
#define SLOT  49536                  // 258*192
#define LDS1  (3 * SLOT)             // 148608 B rolling 3-row window

typedef short  v8s __attribute__((ext_vector_type(8)));   // 8 x bf16 (4 VGPRs)
typedef float  v4f __attribute__((ext_vector_type(4)));   // MFMA acc frag

static __device__ __forceinline__ unsigned short f2bf(float f) {
    __hip_bfloat16 h = __float2bfloat16(f);   // RNE
    return *(unsigned short*)&h;
}
static __device__ __forceinline__ float bf2f(unsigned short u) {
    return __uint_as_float(((unsigned int)u) << 16);
}

// ---------------------------------------------------------------------------
// prep: w_body fp32 -> wbf2 fragment-major bf16.
// frag f = (tap*3 + ks)*3 + mf; within frag, lane = l4*16+l15 holds
// A[co = mf*16+l15][ci = ks*32 + l4*8 + e] at byte lane*16 + e*2.
// ---------------------------------------------------------------------------
__global__ void prep_weights(const float* __restrict__ wb, unsigned short* __restrict__ wbf2) {
    int o = blockIdx.x * blockDim.x + threadIdx.x;      // flat over 81*512
    if (o >= 81 * 512) return;
    int f = o >> 9, r = o & 511;
    int lane = r >> 3, e = r & 7;
    int l4 = lane >> 4, l15 = lane & 15;
    int mf = f % 3, ks = (f / 3) % 3, tap = f / 9;
    int co = mf * 16 + l15;
    int ci = ks * 32 + l4 * 8 + e;
    wbf2[o] = f2bf(wb[(co * CIN + ci) * 9 + tap]);
}

// ---------------------------------------------------------------------------
// conv1_direct staging helpers.
// Task (c, q): load 8 x float4 = channels 8c..8c+7, pixels w = 4q..4q+3 of
// input row r (contiguous along w -> perfectly coalesced 1KB/wave-instr).
// Pack to 4 LDS cells px = 4q+1+k (register transpose via component k).
// ---------------------------------------------------------------------------
static __device__ __forceinline__ void stage_load(const float* __restrict__ xb, int r,
                                                  int c, int q, float4* f) {
    const bool rok = ((unsigned)r < 256u);
    const float* g = xb + (((size_t)(c << 3)) << 16) + (r << 8) + (q << 2);
#pragma unroll
    for (int e = 0; e < 8; ++e)
        f[e] = rok ? *(const float4*)(g + (((size_t)e) << 16))
                   : make_float4(0.f, 0.f, 0.f, 0.f);
}

static __device__ __forceinline__ void stage_write(char* __restrict__ slot,
                                                   int c, int q, const float4* f) {
    const float* fp = (const float*)f;
#pragma unroll
    for (int k = 0; k < 4; ++k) {
        const int px = 4 * q + 1 + k;                       // px&3 == (1+k)&3
        const unsigned ad = (unsigned)(px * 192 + ((c ^ ((1 + k) & 3)) << 4));
        uint4 d;
        d.x = f2bf(fp[0 * 4 + k]) | ((unsigned)f2bf(fp[1 * 4 + k]) << 16);
        d.y = f2bf(fp[2 * 4 + k]) | ((unsigned)f2bf(fp[3 * 4 + k]) << 16);
        d.z = f2bf(fp[4 * 4 + k]) | ((unsigned)f2bf(fp[5 * 4 + k]) << 16);
        d.w = f2bf(fp[6 * 4 + k]) | ((unsigned)f2bf(fp[7 * 4 + k]) << 16);
        *(uint4*)(slot + ad) = d;
    }
}

// One kh row of the implicit GEMM for a 32-px wave: 3 mf x 2 nf accs.
static __device__ __forceinline__ void kh_block2(const char* __restrict__ bb0,
                                                 const char* __restrict__ apl,
                                                 int kh, const unsigned* U, v4f* acc) {
#pragma unroll
    for (int kw = 0; kw < 3; ++kw) {
        const char* bb = bb0 + U[kw];
#pragma unroll
        for (int ks = 0; ks < 3; ++ks) {
            const int f0 = ((kh * 3 + kw) * 3 + ks) * 3;
            v8s a0 = *(const v8s*)(apl + (f0 + 0) * 1024);
            v8s a1 = *(const v8s*)(apl + (f0 + 1) * 1024);
            v8s a2 = *(const v8s*)(apl + (f0 + 2) * 1024);
            v8s b0 = *(const v8s*)(bb + ks * 64);
            v8s b1 = *(const v8s*)(bb + ks * 64 + 3072);
            acc[0] = __builtin_amdgcn_mfma_f32_16x16x32_bf16(a0, b0, acc[0], 0, 0, 0);
            acc[1] = __builtin_amdgcn_mfma_f32_16x16x32_bf16(a0, b1, acc[1], 0, 0, 0);
            acc[2] = __builtin_amdgcn_mfma_f32_16x16x32_bf16(a1, b0, acc[2], 0, 0, 0);
            acc[3] = __builtin_amdgcn_mfma_f32_16x16x32_bf16(a1, b1, acc[3], 0, 0, 0);
            acc[4] = __builtin_amdgcn_mfma_f32_16x16x32_bf16(a2, b0, acc[4], 0, 0, 0);
            acc[5] = __builtin_amdgcn_mfma_f32_16x16x32_bf16(a2, b1, acc[5], 0, 0, 0);
        }
    }
}

// ---------------------------------------------------------------------------
// conv1_direct: fused transpose + conv1. Reads x (fp32 NCHW) directly via
// float4-along-W staging into a 3-slot rolling LDS window (bf16, swizzled).
// 512 threads = 8 waves (2/SIMD); wave = 32 px. T14: issue row h+2 loads
// before compute of row h; pack+ds_write after the barrier. Writes y_us
// bf16 pixel-unshuffled. Grid 32x8 = 256 blocks (1/CU).
// ---------------------------------------------------------------------------
__global__ __launch_bounds__(512) void conv1_direct(const float* __restrict__ x,
                                                    const unsigned short* __restrict__ wbf2,
                                                    unsigned short* __restrict__ y_us) {
    extern __shared__ char lds[];
    const int band = blockIdx.x;        // 0..31
    const int b    = blockIdx.y;        // 0..7
    const int h0   = band * 8;
    const int tid  = threadIdx.x;
    const int lane = tid & 63;
    const int l15  = lane & 15;
    const int l4   = lane >> 4;
    const int w0   = (tid >> 6) * 32;   // wave px base

    const char*  apl = (const char*)wbf2 + lane * 16;
    const float* xb  = x + (((size_t)b * CIN) << 16);

    // staging task assignment: task tau = c*64 + q; thread does tau=tid
    // (c=wave, q=lane) and, for tid<256, tau=512+tid (c=8+wv, q=lane).
    const int c1 = tid >> 6, q1 = lane;
    const bool two = (tid < 256);
    const int c2 = 8 + (tid >> 6);      // only used when two

    // B-frag read offsets (swizzle folded; ks*4 commutes with low-2-bit XOR)
    unsigned U[3];
#pragma unroll
    for (int kw = 0; kw < 3; ++kw) {
        const int p = w0 + l15 + kw;
        U[kw] = (unsigned)(p * 192 + ((l4 ^ (p & 3)) << 4));
    }

    char* s0 = lds;
    char* s1 = lds + SLOT;
    char* s2 = lds + 2 * SLOT;

    // zero px=0 / px=257 halo cells of all 3 slots (ws poisoned each launch)
    if (tid < 72) {
        int s = tid / 24, rem = tid % 24;
        int c = rem % 12, px = (rem / 12) * 257;
        *(uint4*)(lds + s * SLOT + px * 192 + ((c ^ (px & 3)) << 4)) =
            make_uint4(0u, 0u, 0u, 0u);
    }

    // prologue: stage input rows h0-1, h0, h0+1 into slots 0,1,2
    {
        float4 f[8];
#pragma unroll
        for (int pr = 0; pr < 3; ++pr) {
            const int r = h0 - 1 + pr;
            char* slot = lds + pr * SLOT;
            stage_load(xb, r, c1, q1, f);
            stage_write(slot, c1, q1, f);
            if (two) {
                stage_load(xb, r, c2, q1, f);
                stage_write(slot, c2, q1, f);
            }
        }
    }
    __syncthreads();

    float4 stA[8], stB[8];
#pragma unroll 1
    for (int i = 0; i < 8; ++i) {
        const int h = h0 + i;
        const bool do_stage = (i < 7);

        // T14 issue-early: loads for input row h+2 (consumed after barrier)
        if (do_stage) {
            stage_load(xb, h + 2, c1, q1, stA);
            if (two) stage_load(xb, h + 2, c2, q1, stB);
        }

        v4f acc[6];
#pragma unroll
        for (int k = 0; k < 6; ++k) acc[k] = (v4f){0.f, 0.f, 0.f, 0.f};

        kh_block2(s0, apl, 0, U, acc);      // input row h-1
        kh_block2(s1, apl, 1, U, acc);      // input row h
        kh_block2(s2, apl, 2, U, acc);      // input row h+1

        // epilogue: y_us[b][co*4+2dy+dx][h>>1][Wp>>1]
        const int dy = h & 1, hp1 = h >> 1;
#pragma unroll
        for (int mf = 0; mf < 3; ++mf) {
#pragma unroll
            for (int nf = 0; nf < 2; ++nf) {
                const int Wp = w0 + nf * 16 + l15;
                const int dx = Wp & 1, wq = Wp >> 1;
#pragma unroll
                for (int r = 0; r < 4; ++r) {
                    const int co = mf * 16 + l4 * 4 + r;
                    const int n  = co * 4 + dy * 2 + dx;
                    y_us[(((size_t)b * NCH + n) << 14) + (hp1 << 7) + wq] =
                        f2bf(acc[mf * 2 + nf][r]);
                }
            }
        }

        __syncthreads();                    // all waves done reading s0
        if (do_stage) {
            stage_write(s0, c1, q1, stA);   // row h+2 into freed slot
            if (two) stage_write(s0, c2, q1, stB);
        }
        __syncthreads();                    // row h+2 visible
        char* tmp = s0; s0 = s1; s1 = s2; s2 = tmp;
    }
}

// ---------------------------------------------------------------------------
// conv2_v2: grouped 3x3 over (y_us[n] bf16, mask-unshuffled[n&3]).
// Block = 4 planes sharing one mask quarter q, 16 rows x 128 cols.
// Mask tile staged ONCE, reused 4x (mask HBM fetch /4); div-free 2D staging.
// Grid 3072 blocks: bid = ((b*4+q)*12+g)*8 + band; planes n = 16g+4p+q.
// ---------------------------------------------------------------------------
#define T2H 16
__global__ __launch_bounds__(256) void conv2_v2(
    const unsigned short* __restrict__ y_us, const float* __restrict__ mask,
    const float* __restrict__ wproj, float* __restrict__ out)
{
    __shared__ float          mt[(T2H + 2) * 132];
    __shared__ unsigned short yt[4][(T2H + 2) * 132];

    const int tid  = threadIdx.x;
    const int bid  = blockIdx.x;            // 0..3071
    const int band = bid & 7;
    const int t1   = bid >> 3;              // 0..383
    const int g    = t1 % 12;
    const int t2   = t1 / 12;               // 0..31
    const int q    = t2 & 3;
    const int b    = t2 >> 2;
    const int h0   = band * T2H;
    const int dy   = q >> 1, dx = q & 1;

    const int tx = tid & 127;
    const int ty = tid >> 7;                // 0/1

    // ---- stage mask quarter tile (once) ----
    const float* mk = mask + ((size_t)b << 16);
    for (int ly = ty; ly < T2H + 2; ly += 2) {
        const int gy = h0 - 1 + ly;
        const bool rok = ((unsigned)gy < (unsigned)HO);
        {
            const int lx = tx, gx = lx - 1;
            const bool ok = rok && ((unsigned)gx < (unsigned)WO);
            mt[ly * 132 + lx] = ok ? mk[((2 * gy + dy) << 8) + (2 * gx + dx)] : 0.f;
        }
        if (tx < 2) {
            const int lx = 128 + tx, gx = lx - 1;
            const bool ok = rok && ((unsigned)gx < (unsigned)WO);
            mt[ly * 132 + lx] = ok ? mk[((2 * gy + dy) << 8) + (2 * gx + dx)] : 0.f;
        }
    }

    // ---- stage 4 y planes ----
#pragma unroll
    for (int p = 0; p < 4; ++p) {
        const int n = 16 * g + 4 * p + q;
        const unsigned short* yc = y_us + ((size_t)(b * NCH + n) << 14);
        for (int ly = ty; ly < T2H + 2; ly += 2) {
            const int gy = h0 - 1 + ly;
            const bool rok = ((unsigned)gy < (unsigned)HO);
            {
                const int lx = tx, gx = lx - 1;
                const bool ok = rok && ((unsigned)gx < (unsigned)WO);
                yt[p][ly * 132 + lx] = ok ? yc[(gy << 7) + gx] : (unsigned short)0;
            }
            if (tx < 2) {
                const int lx = 128 + tx, gx = lx - 1;
                const bool ok = rok && ((unsigned)gx < (unsigned)WO);
                yt[p][ly * 132 + lx] = ok ? yc[(gy << 7) + gx] : (unsigned short)0;
            }
        }
    }
    __syncthreads();

    const int rbase = ty * 8;

#pragma unroll
    for (int p = 0; p < 4; ++p) {
        const int n = 16 * g + 4 * p + q;
        const float* wp = wproj + n * 18;   // block-uniform -> s_load
        float wy[9], wm[9];
#pragma unroll
        for (int j = 0; j < 9; ++j) { wy[j] = wp[j]; wm[j] = wp[9 + j]; }

        const unsigned short* ytp = yt[p];

        float y0[3], y1[3], m0[3], m1[3];
#pragma unroll
        for (int kw = 0; kw < 3; ++kw) {
            y0[kw] = bf2f(ytp[(rbase + 0) * 132 + tx + kw]);
            m0[kw] = mt[(rbase + 0) * 132 + tx + kw];
            y1[kw] = bf2f(ytp[(rbase + 1) * 132 + tx + kw]);
            m1[kw] = mt[(rbase + 1) * 132 + tx + kw];
        }

#pragma unroll
        for (int i = 0; i < 8; ++i) {
            float y2[3], m2[3];
#pragma unroll
            for (int kw = 0; kw < 3; ++kw) {
                y2[kw] = bf2f(ytp[(rbase + i + 2) * 132 + tx + kw]);
                m2[kw] = mt[(rbase + i + 2) * 132 + tx + kw];
            }
            float acc = 0.f;
#pragma unroll
            for (int kw = 0; kw < 3; ++kw) {
                acc = fmaf(wy[0 * 3 + kw], y0[kw], acc);
                acc = fmaf(wm[0 * 3 + kw], m0[kw], acc);
            }
#pragma unroll
            for (int kw = 0; kw < 3; ++kw) {
                acc = fmaf(wy[1 * 3 + kw], y1[kw], acc);
                acc = fmaf(wm[1 * 3 + kw], m1[kw], acc);
            }
#pragma unroll
            for (int kw = 0; kw < 3; ++kw) {
                acc = fmaf(wy[2 * 3 + kw], y2[kw], acc);
                acc = fmaf(wm[2 * 3 + kw], m2[kw], acc);
            }
            const int oy = h0 + rbase + i;
            out[((size_t)(b * NCH + n) << 14) + (oy << 7) + tx] = acc;
#pragma unroll
            for (int kw = 0; kw < 3; ++kw) {
                y0[kw] = y1[kw]; y1[kw] = y2[kw];
                m0[kw] = m1[kw]; m1[kw] = m2[kw];
            }
        }
    }
}

// ---------------------------------------------------------------------------
extern "C" void kernel_launch(void* const* d_in, const int* in_sizes, int n_in,
                              void* d_out, int out_size, void* d_ws, size_t ws_size,
                              hipStream_t stream) {
    const float* x      = (const float*)d_in[0];   // (8,96,256,256)
    const float* mask   = (const float*)d_in[1];   // (8,1,256,256)
    const float* w_body = (const float*)d_in[2];   // (48,96,3,3)
    const float* w_proj = (const float*)d_in[3];   // (192,2,3,3)
    float* out = (float*)d_out;                    // (8,192,128,128)

    // workspace layout
    char* p = (char*)d_ws;
    unsigned short* wbf2 = (unsigned short*)p;   p += (81 * 512 * 2 + 255) & ~255ull;  // 83 KB
    unsigned short* y_us = (unsigned short*)p;   // 50.3 MB bf16

    (void)hipFuncSetAttribute(reinterpret_cast<const void*>(conv1_direct),
                              hipFuncAttributeMaxDynamicSharedMemorySize, LDS1);

    {   int nel = 81 * 512;
        prep_weights<<<(nel + 255) / 256, 256, 0, stream>>>(w_body, wbf2); }
    {   dim3 grid(32, B_);
        conv1_direct<<<grid, 512, LDS1, stream>>>(x, wbf2, y_us); }
    {   conv2_v2<<<B_ * 4 * 12 * (HO / T2H), 256, 0, stream>>>(y_us, mask, w_proj, out); }
}

// Round 6
// 434.237 us; speedup vs baseline: 1.3007x; 1.3007x over previous
//
#include <hip/hip_runtime.h>
#include <hip/hip_bf16.h>
#include <cstddef>
#include <cstdint>

#define B_   8
#define CIN  96
#define H_   256
#define W_   256
#define CO1  48          // conv1 output channels
#define NCH  192         // final output channels (CO1*4)
#define HO   128
#define WO   128

// xt row image: 258 px-major cells of 12 chunks (8 bf16 = 16B), swizzled
// cell(px,c) at px*192 + ((c ^ (px&3))<<4). 49536B used, padded to 49 KiB
// so DMA = exactly 49 x (64 lanes x 16B) instructions.
#define IMG   50176                  // 49*1024
#define IMGV  (IMG / 16)             // 3136 uint4
#define LDS1  (3 * IMG)              // conv1 rolling window: 150528 B

typedef short  v8s __attribute__((ext_vector_type(8)));   // 8 x bf16 (4 VGPRs)
typedef float  v4f __attribute__((ext_vector_type(4)));   // MFMA acc frag

static __device__ __forceinline__ unsigned short f2bf(float f) {
    __hip_bfloat16 h = __float2bfloat16(f);   // RNE
    return *(unsigned short*)&h;
}
static __device__ __forceinline__ float bf2f(unsigned short u) {
    return __uint_as_float(((unsigned int)u) << 16);
}

// ---------------------------------------------------------------------------
// prep: w_body fp32 -> wbf2 fragment-major bf16.
// frag f = (tap*3 + ks)*3 + mf; within frag, lane = l4*16+l15 holds
// A[co = mf*16+l15][ci = ks*32 + l4*8 + e] at byte lane*16 + e*2.
// Each A-frag is a contiguous 1KB -> conv1 A-loads are lane-linear dwordx4.
// ---------------------------------------------------------------------------
__global__ void prep_weights(const float* __restrict__ wb, unsigned short* __restrict__ wbf2) {
    int o = blockIdx.x * blockDim.x + threadIdx.x;      // flat over 81*512
    if (o >= 81 * 512) return;
    int f = o >> 9, r = o & 511;
    int lane = r >> 3, e = r & 7;
    int l4 = lane >> 4, l15 = lane & 15;
    int mf = f % 3, ks = (f / 3) % 3, tap = f / 9;
    int co = mf * 16 + l15;
    int ci = ks * 32 + l4 * 8 + e;
    wbf2[o] = f2bf(wb[(co * CIN + ci) * 9 + tap]);
}

// ---------------------------------------------------------------------------
// transpose_x: x (8,96,256,256) fp32 NCHW -> xt row images (8, 258, IMG).
// Image index ri = input row + 1; ri 0 / 257 are zero halo rows.
// LDS-mediated: coalesced loads -> f2bf pack -> swizzled ds_write_b128 ->
// linear uint4 stream-out (perfectly coalesced global writes).
// ---------------------------------------------------------------------------
__global__ __launch_bounds__(256) void transpose_x(const float* __restrict__ x,
                                                   char* __restrict__ xt) {
    extern __shared__ char lds[];
    const int ri = blockIdx.x;          // 0..257
    const int b  = blockIdx.y;
    const int t  = threadIdx.x;

    // zero whole image (halo px0/px257 cells, halo rows, pad)
#pragma unroll
    for (int k = 0; k < 13; ++k) {
        int s = t + 256 * k;
        if (s < IMGV) ((uint4*)lds)[s] = make_uint4(0u, 0u, 0u, 0u);
    }
    __syncthreads();

    const int h = ri - 1;
    if (0 <= h && h < 256) {            // block-uniform condition
        const float* xp = x + (((size_t)b * CIN) << 16) + (h << 8) + t;
        const int px = t + 1;
        char* cbase = lds + px * 192;
        const int s = px & 3;
#pragma unroll
        for (int c = 0; c < 12; ++c) {
            float f[8];
#pragma unroll
            for (int j = 0; j < 8; ++j)
                f[j] = xp[((size_t)(8 * c + j)) << 16];
            uint4 d;
            d.x = f2bf(f[0]) | ((unsigned)f2bf(f[1]) << 16);
            d.y = f2bf(f[2]) | ((unsigned)f2bf(f[3]) << 16);
            d.z = f2bf(f[4]) | ((unsigned)f2bf(f[5]) << 16);
            d.w = f2bf(f[6]) | ((unsigned)f2bf(f[7]) << 16);
            *(uint4*)(cbase + ((c ^ s) << 4)) = d;
        }
    }
    __syncthreads();

    const uint4* sp = (const uint4*)lds;
    uint4* dp = (uint4*)(xt + ((size_t)b * 258 + ri) * IMG);
#pragma unroll
    for (int k = 0; k < 13; ++k) {
        int s = t + 256 * k;
        if (s < IMGV) dp[s] = sp[s];
    }
}

// ---------------------------------------------------------------------------
// conv1 helpers
// ---------------------------------------------------------------------------
static __device__ __forceinline__ void dma_row(char* lds_base, const char* gsrc,
                                               int wv, int lane) {
    // 49 x global_load_lds dwordx4; waves 0..2 take 13, wave 3 takes 10.
    const int k0 = wv * 13;
    const int k1 = (k0 + 13 < 49) ? (k0 + 13) : 49;
    for (int k = k0; k < k1; ++k) {
        __builtin_amdgcn_global_load_lds(
            (const __attribute__((address_space(1))) unsigned int*)(gsrc + k * 1024 + lane * 16),
            (__attribute__((address_space(3))) unsigned int*)(lds_base + k * 1024),
            16, 0, 0);
    }
}

static __device__ __forceinline__ void kh_block(const char* bb0, const char* apl,
                                                int kh, const unsigned* U, v4f* acc) {
#pragma unroll
    for (int kw = 0; kw < 3; ++kw) {
        const char* bb = bb0 + U[kw];
#pragma unroll
        for (int ks = 0; ks < 3; ++ks) {
            const int f0 = ((kh * 3 + kw) * 3 + ks) * 3;
            v8s a0 = *(const v8s*)(apl + (f0 + 0) * 1024);
            v8s a1 = *(const v8s*)(apl + (f0 + 1) * 1024);
            v8s a2 = *(const v8s*)(apl + (f0 + 2) * 1024);
            v8s b0 = *(const v8s*)(bb + ks * 64 + 0 * 3072);
            v8s b1 = *(const v8s*)(bb + ks * 64 + 1 * 3072);
            v8s b2 = *(const v8s*)(bb + ks * 64 + 2 * 3072);
            v8s b3 = *(const v8s*)(bb + ks * 64 + 3 * 3072);
            acc[0]  = __builtin_amdgcn_mfma_f32_16x16x32_bf16(a0, b0, acc[0],  0, 0, 0);
            acc[1]  = __builtin_amdgcn_mfma_f32_16x16x32_bf16(a0, b1, acc[1],  0, 0, 0);
            acc[2]  = __builtin_amdgcn_mfma_f32_16x16x32_bf16(a0, b2, acc[2],  0, 0, 0);
            acc[3]  = __builtin_amdgcn_mfma_f32_16x16x32_bf16(a0, b3, acc[3],  0, 0, 0);
            acc[4]  = __builtin_amdgcn_mfma_f32_16x16x32_bf16(a1, b0, acc[4],  0, 0, 0);
            acc[5]  = __builtin_amdgcn_mfma_f32_16x16x32_bf16(a1, b1, acc[5],  0, 0, 0);
            acc[6]  = __builtin_amdgcn_mfma_f32_16x16x32_bf16(a1, b2, acc[6],  0, 0, 0);
            acc[7]  = __builtin_amdgcn_mfma_f32_16x16x32_bf16(a1, b3, acc[7],  0, 0, 0);
            acc[8]  = __builtin_amdgcn_mfma_f32_16x16x32_bf16(a2, b0, acc[8],  0, 0, 0);
            acc[9]  = __builtin_amdgcn_mfma_f32_16x16x32_bf16(a2, b1, acc[9],  0, 0, 0);
            acc[10] = __builtin_amdgcn_mfma_f32_16x16x32_bf16(a2, b2, acc[10], 0, 0, 0);
            acc[11] = __builtin_amdgcn_mfma_f32_16x16x32_bf16(a2, b3, acc[11], 0, 0, 0);
        }
    }
}

// ---------------------------------------------------------------------------
// conv1_dma: full-width 8-row band per block (grid 32x8 = 256 = 1/CU).
// 3-slot rolling LDS window filled by global_load_lds from xt images.
// Per row: kh0,kh1 -> [vmcnt(0) drain own DMA; s_barrier] -> issue DMA(h+2)
// into freed slot -> kh2 -> epilogue. DMA flight ~1 row; one barrier/row.
// Identical to the round-4 version that measured best.
// ---------------------------------------------------------------------------
__global__ __launch_bounds__(256) void conv1_dma(const char* __restrict__ xt,
                                                 const unsigned short* __restrict__ wbf2,
                                                 unsigned short* __restrict__ y_us) {
    extern __shared__ char lds[];
    const int band = blockIdx.x;        // 0..31
    const int b    = blockIdx.y;        // 0..7
    const int h0   = band * 8;
    const int tid  = threadIdx.x;
    const int lane = tid & 63;
    const int wv   = tid >> 6;
    const int l15  = lane & 15;
    const int l4   = lane >> 4;
    const int w0   = wv * 64;

    const char* apl    = (const char*)wbf2 + lane * 16;
    const char* xrows  = xt + (size_t)b * 258 * IMG;    // image idx = input row + 1

    unsigned U[3];
#pragma unroll
    for (int kw = 0; kw < 3; ++kw) {
        int p = w0 + l15 + kw;
        U[kw] = (unsigned)(p * 192 + ((l4 ^ (p & 3)) << 4));
    }

    char* s0 = lds;
    char* s1 = lds + IMG;
    char* s2 = lds + 2 * IMG;

    // prologue: rows h0-1, h0 landed+barriered; row h0+1 left in flight
    dma_row(s0, xrows + (size_t)(h0)     * IMG, wv, lane);
    dma_row(s1, xrows + (size_t)(h0 + 1) * IMG, wv, lane);
    asm volatile("s_waitcnt vmcnt(0)" ::: "memory");
    __builtin_amdgcn_s_barrier();
    dma_row(s2, xrows + (size_t)(h0 + 2) * IMG, wv, lane);

#pragma unroll 1
    for (int i = 0; i < 8; ++i) {
        const int h = h0 + i;
        v4f acc[12];
#pragma unroll
        for (int k = 0; k < 12; ++k) acc[k] = (v4f){0.f, 0.f, 0.f, 0.f};

        kh_block(s0, apl, 0, U, acc);       // input row h-1 (old slot)
        kh_block(s1, apl, 1, U, acc);       // input row h

        asm volatile("s_waitcnt vmcnt(0)" ::: "memory");   // own DMA(h+1) done
        __builtin_amdgcn_s_barrier();                       // all waves' done; s0 free
        __builtin_amdgcn_sched_barrier(0);

        if (i < 7)
            dma_row(s0, xrows + (size_t)(h + 3) * IMG, wv, lane);  // input row h+2

        kh_block(s2, apl, 2, U, acc);       // input row h+1

        // epilogue: D row = co = mf*16 + l4*4 + r ; D col = px = w0 + nf*16 + l15
        const int dy = h & 1, hp1 = h >> 1;
#pragma unroll
        for (int mf = 0; mf < 3; ++mf) {
#pragma unroll
            for (int nf = 0; nf < 4; ++nf) {
                const int Wp = w0 + nf * 16 + l15;
                const int dx = Wp & 1, wq = Wp >> 1;
#pragma unroll
                for (int r = 0; r < 4; ++r) {
                    const int co = mf * 16 + l4 * 4 + r;
                    const int n  = co * 4 + dy * 2 + dx;
                    y_us[(((size_t)b * NCH + n) << 14) + (hp1 << 7) + wq] =
                        f2bf(acc[mf * 4 + nf][r]);
                }
            }
        }

        char* tmp = s0; s0 = s1; s1 = s2; s2 = tmp;
    }
}

// ---------------------------------------------------------------------------
// conv2_v3: same block decomposition as the round-4 conv2_kernel (one
// (b,n) plane x 16 rows per block, 12288 blocks) and bit-identical math,
// but vectorized staging: y via uint4 (8 bf16) loads, mask via 4x float4
// aligned loads with stride-2 extract (dx handled by uniform branch).
// Tile stored PRE-CONVERTED as f32 in LDS ([18][136], interior at col 4,
// 16B-aligned float4 stores, conflict-free reads) -> zero converts and
// no bounds checks in the inner loop.
// ---------------------------------------------------------------------------
#define T2H 16
__global__ __launch_bounds__(256) void conv2_v3(
    const unsigned short* __restrict__ y_us, const float* __restrict__ mask,
    const float* __restrict__ wproj, float* __restrict__ out)
{
    __shared__ float yt[18 * 136];
    __shared__ float mt[18 * 136];

    const int tid  = threadIdx.x;
    const int bid  = blockIdx.x;            // 0..12287
    const int band = bid & 7;
    const int bn   = bid >> 3;              // b*192 + n
    const int b    = bn / NCH;
    const int n    = bn - b * NCH;
    const int h0   = band * T2H;
    const int q    = n & 3, dy = q >> 1, dx = q & 1;

    const unsigned short* yc = y_us + ((size_t)bn << 14);

    // ---- staging: 288 tasks = 18 rows x 16 col-groups of 8 ----
    for (int task = tid; task < 288; task += 256) {
        const int ly = task >> 4;           // 0..17
        const int j  = task & 15;           // col group: gx = 8j..8j+7
        const int gy = h0 - 1 + ly;
        float yv[8], mv[8];
        if ((unsigned)gy < (unsigned)HO) {
            uint4 yd = *(const uint4*)(yc + (gy << 7) + (j << 3));
            const unsigned short* ys = (const unsigned short*)&yd;
#pragma unroll
            for (int e = 0; e < 8; ++e) yv[e] = bf2f(ys[e]);
            // mask cols 16j..16j+15 of row 2gy+dy; need cols 16j+dx+2k
            const float* mrow = mask + (((size_t)b) << 16)
                                     + (((size_t)(2 * gy + dy)) << 8) + (j << 4);
            float4 m0 = ((const float4*)mrow)[0];
            float4 m1 = ((const float4*)mrow)[1];
            float4 m2 = ((const float4*)mrow)[2];
            float4 m3 = ((const float4*)mrow)[3];
            if (dx == 0) {                  // block-uniform branch
                mv[0] = m0.x; mv[1] = m0.z; mv[2] = m1.x; mv[3] = m1.z;
                mv[4] = m2.x; mv[5] = m2.z; mv[6] = m3.x; mv[7] = m3.z;
            } else {
                mv[0] = m0.y; mv[1] = m0.w; mv[2] = m1.y; mv[3] = m1.w;
                mv[4] = m2.y; mv[5] = m2.w; mv[6] = m3.y; mv[7] = m3.w;
            }
        } else {
#pragma unroll
            for (int e = 0; e < 8; ++e) { yv[e] = 0.f; mv[e] = 0.f; }
        }
        const int base = ly * 136 + 4 + (j << 3);     // byte 16B-aligned
        *(float4*)&yt[base]     = make_float4(yv[0], yv[1], yv[2], yv[3]);
        *(float4*)&yt[base + 4] = make_float4(yv[4], yv[5], yv[6], yv[7]);
        *(float4*)&mt[base]     = make_float4(mv[0], mv[1], mv[2], mv[3]);
        *(float4*)&mt[base + 4] = make_float4(mv[4], mv[5], mv[6], mv[7]);
    }
    // halo cols: gx=-1 -> col 3, gx=128 -> col 132 (zero padding)
    if (tid < 36) {
        const int ly = tid >> 1, c = (tid & 1) ? 132 : 3;
        yt[ly * 136 + c] = 0.f;
        mt[ly * 136 + c] = 0.f;
    }
    __syncthreads();

    // ---- weights (block-uniform -> s_load) ----
    const float* wp = wproj + n * 18;
    float wy[9], wm[9];
#pragma unroll
    for (int j = 0; j < 9; ++j) { wy[j] = wp[j]; wm[j] = wp[9 + j]; }

    const int tx    = tid & 127;
    const int ty    = tid >> 7;             // 0/1 -> rows [0..7] / [8..15]
    const int rbase = ty * 8;
    const int cb    = tx + 3;               // tap cols cb..cb+2

    float y0[3], y1[3], m0_[3], m1_[3];
#pragma unroll
    for (int kw = 0; kw < 3; ++kw) {
        y0[kw]  = yt[(rbase + 0) * 136 + cb + kw];
        m0_[kw] = mt[(rbase + 0) * 136 + cb + kw];
        y1[kw]  = yt[(rbase + 1) * 136 + cb + kw];
        m1_[kw] = mt[(rbase + 1) * 136 + cb + kw];
    }

#pragma unroll
    for (int i = 0; i < 8; ++i) {
        float y2[3], m2_[3];
#pragma unroll
        for (int kw = 0; kw < 3; ++kw) {
            y2[kw]  = yt[(rbase + i + 2) * 136 + cb + kw];
            m2_[kw] = mt[(rbase + i + 2) * 136 + cb + kw];
        }
        float acc = 0.f;
#pragma unroll
        for (int kw = 0; kw < 3; ++kw) {
            acc = fmaf(wy[0 * 3 + kw], y0[kw],  acc);
            acc = fmaf(wm[0 * 3 + kw], m0_[kw], acc);
        }
#pragma unroll
        for (int kw = 0; kw < 3; ++kw) {
            acc = fmaf(wy[1 * 3 + kw], y1[kw],  acc);
            acc = fmaf(wm[1 * 3 + kw], m1_[kw], acc);
        }
#pragma unroll
        for (int kw = 0; kw < 3; ++kw) {
            acc = fmaf(wy[2 * 3 + kw], y2[kw],  acc);
            acc = fmaf(wm[2 * 3 + kw], m2_[kw], acc);
        }
        const int oy = h0 + rbase + i;
        out[((size_t)bn << 14) + (oy << 7) + tx] = acc;
#pragma unroll
        for (int kw = 0; kw < 3; ++kw) {
            y0[kw] = y1[kw]; y1[kw] = y2[kw];
            m0_[kw] = m1_[kw]; m1_[kw] = m2_[kw];
        }
    }
}

// ---------------------------------------------------------------------------
extern "C" void kernel_launch(void* const* d_in, const int* in_sizes, int n_in,
                              void* d_out, int out_size, void* d_ws, size_t ws_size,
                              hipStream_t stream) {
    const float* x      = (const float*)d_in[0];   // (8,96,256,256)
    const float* mask   = (const float*)d_in[1];   // (8,1,256,256)
    const float* w_body = (const float*)d_in[2];   // (48,96,3,3)
    const float* w_proj = (const float*)d_in[3];   // (192,2,3,3)
    float* out = (float*)d_out;                    // (8,192,128,128)

    // workspace layout
    char* p = (char*)d_ws;
    unsigned short* wbf2 = (unsigned short*)p;   p += (81 * 512 * 2 + 255) & ~255ull;           // 83 KB
    char*           xt   = p;                    p += ((size_t)B_ * 258 * IMG + 255) & ~255ull; // 103.6 MB
    unsigned short* y_us = (unsigned short*)p;   // 50.3 MB bf16

    (void)hipFuncSetAttribute(reinterpret_cast<const void*>(conv1_dma),
                              hipFuncAttributeMaxDynamicSharedMemorySize, LDS1);

    {   int nel = 81 * 512;
        prep_weights<<<(nel + 255) / 256, 256, 0, stream>>>(w_body, wbf2); }
    {   dim3 grid(258, B_);
        transpose_x<<<grid, 256, IMG, stream>>>(x, xt); }
    {   dim3 grid(32, B_);
        conv1_dma<<<grid, 256, LDS1, stream>>>(xt, wbf2, y_us); }
    {   conv2_v3<<<B_ * NCH * (HO / T2H), 256, 0, stream>>>(y_us, mask, w_proj, out); }
}